// Round 7
// baseline (343.721 us; speedup 1.0000x reference)
//
#include <hip/hip_runtime.h>
#include <stdint.h>

typedef __attribute__((ext_vector_type(8))) short short8;
typedef __attribute__((ext_vector_type(4))) float f32x4;

constexpr int C   = 256;     // MODEL_DIM
constexpr int HID = 128;
constexpr int P   = 32768;   // H*W
constexpr int BN  = 64;      // pixels per block
constexpr int XLD = 280;     // xT row len (bf16 elements): 560B rows, 12-word bank rotation
constexpr int HLD = 136;     // h1T row len

// ws layout (ushort/bf16 elements)
constexpr unsigned OFF_WQ  = 0;
constexpr unsigned OFF_WK  = 65536;
constexpr unsigned OFF_WV  = 131072;
constexpr unsigned OFF_WO  = 196608;
constexpr unsigned OFF_WD2 = 262144;
constexpr unsigned W_TOTAL = 294912;

__device__ __forceinline__ unsigned f2b(float x) {           // f32 -> bf16 bits (RNE)
    unsigned u = __float_as_uint(x);
    return (u + 0x7FFFu + ((u >> 16) & 1u)) >> 16;
}
__device__ __forceinline__ float b2f(unsigned u) {           // bf16 bits (low 16) -> f32
    return __uint_as_float(u << 16);
}

__global__ void cvt_weights(const float* __restrict__ wq, const float* __restrict__ wk,
                            const float* __restrict__ wv, const float* __restrict__ wo,
                            const float* __restrict__ wd2, unsigned short* __restrict__ dst) {
    unsigned i = blockIdx.x * 256 + threadIdx.x;
    if (i >= W_TOTAL) return;
    float v;
    if (i < OFF_WK)       v = wq[i];
    else if (i < OFF_WV)  v = wk[i - OFF_WK];
    else if (i < OFF_WO)  v = wv[i - OFF_WV];
    else if (i < OFF_WD2) v = wo[i - OFF_WO];
    else                  v = wd2[i - OFF_WD2];
    dst[i] = (unsigned short)f2b(v);
}

// Swizzle rule (enumerated <=2-way uniform for ds_read_b128 AND b32 writes):
//   element (row, c) lives at col c ^ (((row>>3)&7)<<3).
// In gemmW row = ni*16+a  -> row>>3 = 2*ni + (a>>3).
// In staging row = 4*(t&15)+pi -> row>>3 = (t&15)>>1.

// acc[mi][ni] += W[row0+mi*16+..][k] * B[ni*16+..][k].  B is LDS [BN][LD].
// ks unroll capped at 2 (spill discipline, rounds 0-4).
template <int K, int LD, int MI, bool SWZ>
__device__ __forceinline__ void gemmW(const unsigned short* __restrict__ W,
                                      const unsigned short* __restrict__ B,
                                      int row0, int a, int q, f32x4 (*acc)[4]) {
#pragma unroll 2
    for (int ks = 0; ks < K / 32; ++ks) {
        const int kb = ks * 32 + q * 8;
        short8 af[MI], bf[4];
#pragma unroll
        for (int mi = 0; mi < MI; ++mi)
            af[mi] = *reinterpret_cast<const short8*>(W + (size_t)(row0 + mi * 16 + a) * K + kb);
#pragma unroll
        for (int ni = 0; ni < 4; ++ni) {
            const int col = SWZ ? (kb ^ (((2 * ni + (a >> 3)) & 7) << 3)) : kb;
            bf[ni] = *reinterpret_cast<const short8*>(B + (ni * 16 + a) * LD + col);
        }
#pragma unroll
        for (int mi = 0; mi < MI; ++mi)
#pragma unroll
            for (int ni = 0; ni < 4; ++ni)
                acc[mi][ni] = __builtin_amdgcn_mfma_f32_16x16x32_bf16(af[mi], bf[ni], acc[mi][ni], 0, 0, 0);
    }
}

// stage f32 (ego+pos) -> bf16 pixel-major LDS with write swizzle (512 threads)
__device__ __forceinline__ void stage_ego(const float* __restrict__ s0,
                                          const float* __restrict__ s1,
                                          int t, int pix0, unsigned short* X) {
    const int cg = t >> 4;        // channel pair
    const int pb = 4 * (t & 15);  // pixel base
    const int swz = (((t & 15) >> 1) & 7) << 3;
#pragma unroll
    for (int k = 0; k < 4; ++k) {
        const int c = 2 * cg + 64 * k;
        const int cs = c ^ swz;
        float4 ra = *reinterpret_cast<const float4*>(s0 + (size_t)c * P + pix0 + pb);
        float4 rb = *reinterpret_cast<const float4*>(s0 + (size_t)(c + 1) * P + pix0 + pb);
        float4 ta = *reinterpret_cast<const float4*>(s1 + (size_t)c * P + pix0 + pb);
        float4 tb = *reinterpret_cast<const float4*>(s1 + (size_t)(c + 1) * P + pix0 + pb);
        ra.x += ta.x; ra.y += ta.y; ra.z += ta.z; ra.w += ta.w;
        rb.x += tb.x; rb.y += tb.y; rb.z += tb.z; rb.w += tb.w;
        const float va[4] = {ra.x, ra.y, ra.z, ra.w};
        const float vb[4] = {rb.x, rb.y, rb.z, rb.w};
#pragma unroll
        for (int pi = 0; pi < 4; ++pi) {
            unsigned pk = f2b(va[pi]) | (f2b(vb[pi]) << 16);
            *reinterpret_cast<unsigned*>(X + (pb + pi) * XLD + cs) = pk;
        }
    }
}

// issue one full col tile (64px x 256ch f32) into 8 float4 regs (32 VGPR)
__device__ __forceinline__ void issue_tile(const float* __restrict__ src, int pix0,
                                           int t, float4* s4) {
    const int cg = t >> 4;
    const int pb = 4 * (t & 15);
#pragma unroll
    for (int k = 0; k < 4; ++k) {
        const int c = 2 * cg + 64 * k;
        s4[2 * k]     = *reinterpret_cast<const float4*>(src + (size_t)c * P + pix0 + pb);
        s4[2 * k + 1] = *reinterpret_cast<const float4*>(src + (size_t)(c + 1) * P + pix0 + pb);
    }
}

// convert tile regs -> bf16 swizzled LDS
__device__ __forceinline__ void convert_tile(unsigned short* X, int t, const float4* s4) {
    const int cg = t >> 4;
    const int pb = 4 * (t & 15);
    const int swz = (((t & 15) >> 1) & 7) << 3;
#pragma unroll
    for (int k = 0; k < 4; ++k) {
        const int cs = (2 * cg + 64 * k) ^ swz;
        const float4 ra = s4[2 * k], rb = s4[2 * k + 1];
        const float va[4] = {ra.x, ra.y, ra.z, ra.w};
        const float vb[4] = {rb.x, rb.y, rb.z, rb.w};
#pragma unroll
        for (int pi = 0; pi < 4; ++pi) {
            unsigned pk = f2b(va[pi]) | (f2b(vb[pi]) << 16);
            *reinterpret_cast<unsigned*>(X + (pb + pi) * XLD + cs) = pk;
        }
    }
}

__global__ __launch_bounds__(512, 2) void dca_mfma(
    const float* __restrict__ ego, const float* __restrict__ dem,
    const float* __restrict__ col,
    const float* __restrict__ w_d1, const float* __restrict__ b_d1,
    const float* __restrict__ b_d2, const float* __restrict__ bq,
    const float* __restrict__ bk, const float* __restrict__ bv,
    const float* __restrict__ bo, const float* __restrict__ pos,
    const unsigned short* __restrict__ wbf, float* __restrict__ out)
{
    // FOUR resident tiles (143 KB): A=qs->col3, B=col0, C=col1, D=h1->col2.
    // Makes the attention loop barrier-free (tiles read-only once staged).
    __shared__ __align__(16) unsigned short xbuf[4 * BN * XLD];
    unsigned short* const bufA = xbuf;
    unsigned short* const bufB = xbuf + 1 * BN * XLD;
    unsigned short* const bufC = xbuf + 2 * BN * XLD;
    unsigned short* const bufD = xbuf + 3 * BN * XLD;

    const int t = threadIdx.x;
    const int w = t >> 6;    // wave 0..7 == head w, owns channels [32w, 32w+32)
    const int l = t & 63;
    const int a = l & 15;
    const int q = l >> 4;
    const int row0 = w * 32;
    const int pix0 = blockIdx.x * BN;

    // ---- stage bf16(ego + pos) -> bufA (swizzled) ----
    stage_ego(ego, pos, t, pix0, bufA);

    // ---- demand MLP: h1 = relu(w_d1 @ dem + b_d1) -> bufD ([BN][HLD], unswizzled) ----
    {
        const int hid0 = 2 * l;
        const float w10 = w_d1[hid0 * 3 + 0], w11 = w_d1[hid0 * 3 + 1], w12 = w_d1[hid0 * 3 + 2];
        const float w20 = w_d1[hid0 * 3 + 3], w21 = w_d1[hid0 * 3 + 4], w22 = w_d1[hid0 * 3 + 5];
        const float bb0 = b_d1[hid0], bb1 = b_d1[hid0 + 1];
#pragma unroll
        for (int k = 0; k < 8; ++k) {
            const int p = w + 8 * k;  // wave-uniform pixel
            float d0 = dem[pix0 + p];
            float d1 = dem[P + pix0 + p];
            float d2v = dem[2 * P + pix0 + p];
            float h0 = fmaxf(bb0 + w10 * d0 + w11 * d1 + w12 * d2v, 0.0f);
            float h1v = fmaxf(bb1 + w20 * d0 + w21 * d1 + w22 * d2v, 0.0f);
            *reinterpret_cast<unsigned*>(bufD + p * HLD + hid0) = f2b(h0) | (f2b(h1v) << 16);
        }
    }
    __syncthreads();                                   // barrier1

    float4 sA[8];                                      // single 32-reg staging window
    issue_tile(col, pix0, t, sA);                      // col0 flies under P1

    f32x4 vacc[2][4];

    // ---- P1: qs = (w_d2 @ h1 + b_d2) + (ego + pos), into bufA ----
#pragma unroll
    for (int mi = 0; mi < 2; ++mi) {
        f32x4 bb = *reinterpret_cast<const f32x4*>(b_d2 + row0 + mi * 16 + q * 4);
#pragma unroll
        for (int ni = 0; ni < 4; ++ni) vacc[mi][ni] = bb;
    }
    gemmW<HID, HLD, 2, false>(wbf + OFF_WD2, bufD, row0, a, q, vacc);
#pragma unroll
    for (int mi = 0; mi < 2; ++mi) {
        const int cb = row0 + mi * 16 + q * 4;
#pragma unroll
        for (int ni = 0; ni < 4; ++ni) {
            const int row = ni * 16 + a;
            const int cs = cb ^ (((2 * ni + (a >> 3)) & 7) << 3);
            unsigned* cell = reinterpret_cast<unsigned*>(bufA + row * XLD + cs);
            unsigned e0 = cell[0], e1 = cell[1];
            float o0 = vacc[mi][ni][0] + b2f(e0 & 0xFFFFu);
            float o1 = vacc[mi][ni][1] + b2f(e0 >> 16);
            float o2 = vacc[mi][ni][2] + b2f(e1 & 0xFFFFu);
            float o3 = vacc[mi][ni][3] + b2f(e1 >> 16);
            cell[0] = f2b(o0) | (f2b(o1) << 16);
            cell[1] = f2b(o2) | (f2b(o3) << 16);
        }
    }
    __syncthreads();                                   // barrier2 (qs published; h1 dead)

    convert_tile(bufB, t, sA);                         // col0 -> B
    issue_tile(col + (size_t)C * P, pix0, t, sA);      // col1 flies under P2

    // ---- P2: q = wq @ qs + bq ----
#pragma unroll
    for (int mi = 0; mi < 2; ++mi) {
        f32x4 bb = *reinterpret_cast<const f32x4*>(bq + row0 + mi * 16 + q * 4);
#pragma unroll
        for (int ni = 0; ni < 4; ++ni) vacc[mi][ni] = bb;
    }
    gemmW<C, XLD, 2, true>(wbf + OFF_WQ, bufA, row0, a, q, vacc);
    unsigned qpk[2][4][2];
#pragma unroll
    for (int mi = 0; mi < 2; ++mi)
#pragma unroll
        for (int ni = 0; ni < 4; ++ni) {
            qpk[mi][ni][0] = f2b(vacc[mi][ni][0]) | (f2b(vacc[mi][ni][1]) << 16);
            qpk[mi][ni][1] = f2b(vacc[mi][ni][2]) | (f2b(vacc[mi][ni][3]) << 16);
        }

    convert_tile(bufC, t, sA);                         // col1 -> C (covered by P2)
    __syncthreads();                                   // barrier3 (B,C ready; A dead)

    issue_tile(col + (size_t)2 * C * P, pix0, t, sA);  // col2, covered by K(tile0)

    // ---- barrier-free fused k/v loop; no-max softmax; V via scale trick in vacc.
    //      Tile n lives in buffer (n+1)&3.  col2 -> D converts at n=0; col3 -> A at n=1;
    //      one mid-loop barrier (top of n=2) publishes them. ----
    float lrun[4];
#pragma unroll
    for (int ni = 0; ni < 4; ++ni) lrun[ni] = 0.0f;
    {
        const f32x4 z = {0.0f, 0.0f, 0.0f, 0.0f};
#pragma unroll
        for (int mi = 0; mi < 2; ++mi)
#pragma unroll
            for (int ni = 0; ni < 4; ++ni) vacc[mi][ni] = z;
    }
#pragma unroll 1
    for (int n = 0; n < 4; ++n) {
        if (n == 2) __syncthreads();                   // D(col2), A(col3) published
        const unsigned short* rb = xbuf + (size_t)((n + 1) & 3) * (BN * XLD);
        // K-gemm (MI=2), dot with q immediately
        float s[4];
#pragma unroll
        for (int ni = 0; ni < 4; ++ni) s[ni] = 0.0f;
        {
            f32x4 kacc[2][4];
#pragma unroll
            for (int mi = 0; mi < 2; ++mi) {
                f32x4 bb = *reinterpret_cast<const f32x4*>(bk + row0 + mi * 16 + q * 4);
#pragma unroll
                for (int ni = 0; ni < 4; ++ni) kacc[mi][ni] = bb;
            }
            gemmW<C, XLD, 2, true>(wbf + OFF_WK, rb, row0, a, q, kacc);
#pragma unroll
            for (int mi = 0; mi < 2; ++mi)
#pragma unroll
                for (int ni = 0; ni < 4; ++ni) {
                    const unsigned u0 = qpk[mi][ni][0], u1 = qpk[mi][ni][1];
                    float ps = s[ni];
                    ps += b2f(u0 & 0xFFFFu) * kacc[mi][ni][0];
                    ps += b2f(u0 >> 16)     * kacc[mi][ni][1];
                    ps += b2f(u1 & 0xFFFFu) * kacc[mi][ni][2];
                    ps += b2f(u1 >> 16)     * kacc[mi][ni][3];
                    s[ni] = ps;
                }
        }
        // staging converts tucked between K and V gemms (latency covered by them)
        if (n == 0) {
            convert_tile(bufD, t, sA);                          // col2 -> D
            issue_tile(col + (size_t)3 * C * P, pix0, t, sA);   // col3, covered by V+K
        }
        if (n == 1) convert_tile(bufA, t, sA);                  // col3 -> A
        float pp[4];
#pragma unroll
        for (int ni = 0; ni < 4; ++ni) {
            float ps = s[ni];
            ps += __shfl_xor(ps, 16);
            ps += __shfl_xor(ps, 32);
            pp[ni] = __expf(ps * 0.17677669529663687f);  // 1/sqrt(32)
            lrun[ni] += pp[ni];
        }
        // V-GEMM merged into running accumulator: vacc = vacc + pp * (Wv @ x)
#pragma unroll
        for (int ni = 0; ni < 4; ++ni) {
            const float ip = 1.0f / pp[ni];
#pragma unroll
            for (int mi = 0; mi < 2; ++mi) vacc[mi][ni] *= ip;
        }
        gemmW<C, XLD, 2, true>(wbf + OFF_WV, rb, row0, a, q, vacc);
#pragma unroll
        for (int ni = 0; ni < 4; ++ni) {
#pragma unroll
            for (int mi = 0; mi < 2; ++mi) vacc[mi][ni] *= pp[ni];
        }
    }
    // normalize; add bv once (sum(attn)=1)
#pragma unroll
    for (int ni = 0; ni < 4; ++ni) {
        float inv = 1.0f / lrun[ni];
#pragma unroll
        for (int mi = 0; mi < 2; ++mi) vacc[mi][ni] *= inv;
    }
#pragma unroll
    for (int mi = 0; mi < 2; ++mi) {
        f32x4 bb = *reinterpret_cast<const f32x4*>(bv + row0 + mi * 16 + q * 4);
#pragma unroll
        for (int ni = 0; ni < 4; ++ni) vacc[mi][ni] += bb;
    }

    // ---- stage attention output into bufB (swizzled), o-GEMM ----
    __syncthreads();                                   // all tiles consumed
#pragma unroll
    for (int mi = 0; mi < 2; ++mi) {
        const int cb = row0 + mi * 16 + q * 4;
#pragma unroll
        for (int ni = 0; ni < 4; ++ni) {
            const int row = ni * 16 + a;
            const int cs = cb ^ (((2 * ni + (a >> 3)) & 7) << 3);
            unsigned* cell = reinterpret_cast<unsigned*>(bufB + row * XLD + cs);
            cell[0] = f2b(vacc[mi][ni][0]) | (f2b(vacc[mi][ni][1]) << 16);
            cell[1] = f2b(vacc[mi][ni][2]) | (f2b(vacc[mi][ni][3]) << 16);
        }
    }
    __syncthreads();
#pragma unroll
    for (int mi = 0; mi < 2; ++mi) {
        f32x4 bb = *reinterpret_cast<const f32x4*>(bo + row0 + mi * 16 + q * 4);
#pragma unroll
        for (int ni = 0; ni < 4; ++ni) vacc[mi][ni] = bb;
    }
    gemmW<C, XLD, 2, true>(wbf + OFF_WO, bufB, row0, a, q, vacc);
#pragma unroll
    for (int mi = 0; mi < 2; ++mi) {
        const int cb = row0 + mi * 16 + q * 4;
#pragma unroll
        for (int ni = 0; ni < 4; ++ni) {
            const int pix = pix0 + ni * 16 + a;
#pragma unroll
            for (int r = 0; r < 4; ++r)
                out[(size_t)(cb + r) * P + pix] = vacc[mi][ni][r];
        }
    }
}

extern "C" void kernel_launch(void* const* d_in, const int* in_sizes, int n_in,
                              void* d_out, int out_size, void* d_ws, size_t ws_size,
                              hipStream_t stream) {
    const float* ego  = (const float*)d_in[0];
    const float* dem  = (const float*)d_in[1];
    const float* col  = (const float*)d_in[2];
    const float* w_d1 = (const float*)d_in[3];
    const float* b_d1 = (const float*)d_in[4];
    const float* w_d2 = (const float*)d_in[5];
    const float* b_d2 = (const float*)d_in[6];
    const float* wq   = (const float*)d_in[7];
    const float* bq   = (const float*)d_in[8];
    const float* wk   = (const float*)d_in[9];
    const float* bk   = (const float*)d_in[10];
    const float* wv   = (const float*)d_in[11];
    const float* bv   = (const float*)d_in[12];
    const float* wo   = (const float*)d_in[13];
    const float* bo   = (const float*)d_in[14];
    const float* pos  = (const float*)d_in[15];
    float* out = (float*)d_out;
    unsigned short* wbf = (unsigned short*)d_ws;

    hipLaunchKernelGGL(cvt_weights, dim3((W_TOTAL + 255) / 256), dim3(256), 0, stream,
                       wq, wk, wv, wo, w_d2, wbf);
    hipLaunchKernelGGL(dca_mfma, dim3(P / BN), dim3(512), 0, stream,
                       ego, dem, col, w_d1, b_d1, b_d2, bq, bk, bv, bo, pos, wbf, out);
}

// Round 8
// 303.982 us; speedup vs baseline: 1.1307x; 1.1307x over previous
//
#include <hip/hip_runtime.h>
#include <stdint.h>

typedef __attribute__((ext_vector_type(8))) short short8;
typedef __attribute__((ext_vector_type(4))) float f32x4;

constexpr int C   = 256;     // MODEL_DIM
constexpr int HID = 128;
constexpr int P   = 32768;   // H*W
constexpr int BN  = 64;      // pixels per block
constexpr int XLD = 280;     // xT row len (bf16 elements)
constexpr int HLD = 136;     // h1T row len

// ws layout (ushort/bf16 elements) -- weights stored in FRAGMENT order:
// per matrix, frag f = row_blk*(K/32)+ks is a contiguous 512-elem (1KB) block;
// element (l, e): W[row_blk*16 + (l&15)][ks*32 + (l>>4)*8 + e].
// af load = base + ks*512 + l*8  -> coalesced 1KB per wave instruction
// (fixes the 512B-stride per-lane scatter that serialized the TA).
constexpr unsigned OFF_WQ  = 0;
constexpr unsigned OFF_WK  = 65536;
constexpr unsigned OFF_WV  = 131072;
constexpr unsigned OFF_WO  = 196608;
constexpr unsigned OFF_WD2 = 262144;
constexpr unsigned W_TOTAL = 294912;

__device__ __forceinline__ unsigned f2b(float x) {           // f32 -> bf16 bits (RNE)
    unsigned u = __float_as_uint(x);
    return (u + 0x7FFFu + ((u >> 16) & 1u)) >> 16;
}
__device__ __forceinline__ float b2f(unsigned u) {           // bf16 bits (low 16) -> f32
    return __uint_as_float(u << 16);
}

__global__ void cvt_weights(const float* __restrict__ wq, const float* __restrict__ wk,
                            const float* __restrict__ wv, const float* __restrict__ wo,
                            const float* __restrict__ wd2, unsigned short* __restrict__ dst) {
    unsigned i = blockIdx.x * 256 + threadIdx.x;
    if (i >= W_TOTAL) return;
    const float* src;
    unsigned o;
    int K;
    if (i < OFF_WK)       { src = wq;  o = i;           K = 256; }
    else if (i < OFF_WV)  { src = wk;  o = i - OFF_WK;  K = 256; }
    else if (i < OFF_WO)  { src = wv;  o = i - OFF_WV;  K = 256; }
    else if (i < OFF_WD2) { src = wo;  o = i - OFF_WO;  K = 256; }
    else                  { src = wd2; o = i - OFF_WD2; K = 128; }
    const unsigned f   = o >> 9;        // fragment index
    const unsigned e512 = o & 511;
    const unsigned l   = e512 >> 3;     // lane 0..63
    const unsigned e   = e512 & 7;
    const unsigned ksn = (unsigned)K / 32;
    const unsigned row_blk = f / ksn;
    const unsigned ks      = f % ksn;
    const unsigned row = row_blk * 16 + (l & 15);
    const unsigned col = ks * 32 + (l >> 4) * 8 + e;
    dst[i] = (unsigned short)f2b(src[row * (unsigned)K + col]);
}

// Swizzle rule (enumerated <=2-way uniform for ds_read_b128 AND b32 writes):
//   element (row, c) lives at col c ^ (((row>>3)&7)<<3).
// In gemmW row = ni*16+a  -> row>>3 = 2*ni + (a>>3).
// In staging row = 4*(t&15)+pi -> row>>3 = (t&15)>>1.

// acc[mi][ni] += W[rows of block row_blk0+mi][k] * B[ni*16+..][k].
// W is in fragment order (see above); af loads are coalesced 1KB.
// ks unroll capped at 2 (spill discipline, rounds 0-4).
template <int K, int LD, int MI, bool SWZ>
__device__ __forceinline__ void gemmW(const unsigned short* __restrict__ W,
                                      const unsigned short* __restrict__ B,
                                      int row_blk0, int a, int q, int l, f32x4 (*acc)[4]) {
    const unsigned short* wf[MI];
#pragma unroll
    for (int mi = 0; mi < MI; ++mi)
        wf[mi] = W + (size_t)(row_blk0 + mi) * (K / 32) * 512 + l * 8;
#pragma unroll 2
    for (int ks = 0; ks < K / 32; ++ks) {
        const int kb = ks * 32 + q * 8;
        short8 af[MI], bf[4];
#pragma unroll
        for (int mi = 0; mi < MI; ++mi)
            af[mi] = *reinterpret_cast<const short8*>(wf[mi] + ks * 512);
#pragma unroll
        for (int ni = 0; ni < 4; ++ni) {
            const int col = SWZ ? (kb ^ (((2 * ni + (a >> 3)) & 7) << 3)) : kb;
            bf[ni] = *reinterpret_cast<const short8*>(B + (ni * 16 + a) * LD + col);
        }
#pragma unroll
        for (int mi = 0; mi < MI; ++mi)
#pragma unroll
            for (int ni = 0; ni < 4; ++ni)
                acc[mi][ni] = __builtin_amdgcn_mfma_f32_16x16x32_bf16(af[mi], bf[ni], acc[mi][ni], 0, 0, 0);
    }
}

// stage f32 (ego+pos) -> bf16 pixel-major LDS with write swizzle (512 threads)
__device__ __forceinline__ void stage_ego(const float* __restrict__ s0,
                                          const float* __restrict__ s1,
                                          int t, int pix0, unsigned short* X) {
    const int cg = t >> 4;        // channel pair
    const int pb = 4 * (t & 15);  // pixel base
    const int swz = (((t & 15) >> 1) & 7) << 3;
#pragma unroll
    for (int k = 0; k < 4; ++k) {
        const int c = 2 * cg + 64 * k;
        const int cs = c ^ swz;
        float4 ra = *reinterpret_cast<const float4*>(s0 + (size_t)c * P + pix0 + pb);
        float4 rb = *reinterpret_cast<const float4*>(s0 + (size_t)(c + 1) * P + pix0 + pb);
        float4 ta = *reinterpret_cast<const float4*>(s1 + (size_t)c * P + pix0 + pb);
        float4 tb = *reinterpret_cast<const float4*>(s1 + (size_t)(c + 1) * P + pix0 + pb);
        ra.x += ta.x; ra.y += ta.y; ra.z += ta.z; ra.w += ta.w;
        rb.x += tb.x; rb.y += tb.y; rb.z += tb.z; rb.w += tb.w;
        const float va[4] = {ra.x, ra.y, ra.z, ra.w};
        const float vb[4] = {rb.x, rb.y, rb.z, rb.w};
#pragma unroll
        for (int pi = 0; pi < 4; ++pi) {
            unsigned pk = f2b(va[pi]) | (f2b(vb[pi]) << 16);
            *reinterpret_cast<unsigned*>(X + (pb + pi) * XLD + cs) = pk;
        }
    }
}

// issue half a col tile (k0 in {0,2}: 2 channel-quads) into 4 float4 regs
__device__ __forceinline__ void issue_half(const float* __restrict__ src, int pix0,
                                           int t, int k0, float4* s4) {
    const int cg = t >> 4;
    const int pb = 4 * (t & 15);
#pragma unroll
    for (int kk = 0; kk < 2; ++kk) {
        const int c = 2 * cg + 64 * (k0 + kk);
        s4[2 * kk]     = *reinterpret_cast<const float4*>(src + (size_t)c * P + pix0 + pb);
        s4[2 * kk + 1] = *reinterpret_cast<const float4*>(src + (size_t)(c + 1) * P + pix0 + pb);
    }
}

// convert half-tile regs -> bf16 swizzled LDS
__device__ __forceinline__ void convert_half(unsigned short* X, int t, int k0,
                                             const float4* s4) {
    const int cg = t >> 4;
    const int pb = 4 * (t & 15);
    const int swz = (((t & 15) >> 1) & 7) << 3;
#pragma unroll
    for (int kk = 0; kk < 2; ++kk) {
        const int cs = (2 * cg + 64 * (k0 + kk)) ^ swz;
        const float4 ra = s4[2 * kk], rb = s4[2 * kk + 1];
        const float va[4] = {ra.x, ra.y, ra.z, ra.w};
        const float vb[4] = {rb.x, rb.y, rb.z, rb.w};
#pragma unroll
        for (int pi = 0; pi < 4; ++pi) {
            unsigned pk = f2b(va[pi]) | (f2b(vb[pi]) << 16);
            *reinterpret_cast<unsigned*>(X + (pb + pi) * XLD + cs) = pk;
        }
    }
}

__global__ __launch_bounds__(512, 2) void dca_mfma(
    const float* __restrict__ ego, const float* __restrict__ dem,
    const float* __restrict__ col,
    const float* __restrict__ w_d1, const float* __restrict__ b_d1,
    const float* __restrict__ b_d2, const float* __restrict__ bq,
    const float* __restrict__ bk, const float* __restrict__ bv,
    const float* __restrict__ bo, const float* __restrict__ pos,
    const unsigned short* __restrict__ wbf, float* __restrict__ out)
{
    // Double-buffered bf16 tile: 2 x 64 x 280 x 2B = 70 KB.
    __shared__ __align__(16) unsigned short xbuf[2 * BN * XLD];
    unsigned short* const x0 = xbuf;
    unsigned short* const x1 = xbuf + BN * XLD;   // h1T overlays here pre-attention

    const int t = threadIdx.x;
    const int w = t >> 6;    // wave 0..7 == head w, owns channels [32w, 32w+32)
    const int l = t & 63;
    const int a = l & 15;
    const int q = l >> 4;
    const int row0 = w * 32;
    const int rb0  = w * 2;  // row block (row0/16)
    const int pix0 = blockIdx.x * BN;

    // ---- stage bf16(ego + pos) -> x0 (swizzled) ----
    stage_ego(ego, pos, t, pix0, x0);

    // ---- demand MLP: h1 = relu(w_d1 @ dem + b_d1) -> x1 region ([BN][HLD], unswizzled) ----
    {
        const int hid0 = 2 * l;
        const float w10 = w_d1[hid0 * 3 + 0], w11 = w_d1[hid0 * 3 + 1], w12 = w_d1[hid0 * 3 + 2];
        const float w20 = w_d1[hid0 * 3 + 3], w21 = w_d1[hid0 * 3 + 4], w22 = w_d1[hid0 * 3 + 5];
        const float bb0 = b_d1[hid0], bb1 = b_d1[hid0 + 1];
#pragma unroll
        for (int k = 0; k < 8; ++k) {
            const int p = w + 8 * k;  // wave-uniform pixel
            float d0 = dem[pix0 + p];
            float d1 = dem[P + pix0 + p];
            float d2v = dem[2 * P + pix0 + p];
            float h0 = fmaxf(bb0 + w10 * d0 + w11 * d1 + w12 * d2v, 0.0f);
            float h1v = fmaxf(bb1 + w20 * d0 + w21 * d1 + w22 * d2v, 0.0f);
            *reinterpret_cast<unsigned*>(x1 + p * HLD + hid0) = f2b(h0) | (f2b(h1v) << 16);
        }
    }
    __syncthreads();

    f32x4 vacc[2][4];

    // ---- P1: qs = (w_d2 @ h1 + b_d2) + (ego + pos), back into x0 ----
#pragma unroll
    for (int mi = 0; mi < 2; ++mi) {
        f32x4 bb = *reinterpret_cast<const f32x4*>(b_d2 + row0 + mi * 16 + q * 4);
#pragma unroll
        for (int ni = 0; ni < 4; ++ni) vacc[mi][ni] = bb;
    }
    gemmW<HID, HLD, 2, false>(wbf + OFF_WD2, x1, rb0, a, q, l, vacc);
#pragma unroll
    for (int mi = 0; mi < 2; ++mi) {
        const int cb = row0 + mi * 16 + q * 4;
#pragma unroll
        for (int ni = 0; ni < 4; ++ni) {
            const int row = ni * 16 + a;
            const int cs = cb ^ (((2 * ni + (a >> 3)) & 7) << 3);
            unsigned* cell = reinterpret_cast<unsigned*>(x0 + row * XLD + cs);
            unsigned e0 = cell[0], e1 = cell[1];
            float o0 = vacc[mi][ni][0] + b2f(e0 & 0xFFFFu);
            float o1 = vacc[mi][ni][1] + b2f(e0 >> 16);
            float o2 = vacc[mi][ni][2] + b2f(e1 & 0xFFFFu);
            float o3 = vacc[mi][ni][3] + b2f(e1 >> 16);
            cell[0] = f2b(o0) | (f2b(o1) << 16);
            cell[1] = f2b(o2) | (f2b(o3) << 16);
        }
    }
    __syncthreads();          // qs published; h1T dead -> x1 reusable

    float4 sA[4], sB[4];      // half-tile staging regs (16 each)
    issue_half(col, pix0, t, 0, sA);        // tile0 half A under P2

    // ---- P2: q = wq @ qs + bq ----
#pragma unroll
    for (int mi = 0; mi < 2; ++mi) {
        f32x4 bb = *reinterpret_cast<const f32x4*>(bq + row0 + mi * 16 + q * 4);
#pragma unroll
        for (int ni = 0; ni < 4; ++ni) vacc[mi][ni] = bb;
    }
    gemmW<C, XLD, 2, true>(wbf + OFF_WQ, x0, rb0, a, q, l, vacc);
    unsigned qpk[2][4][2];
#pragma unroll
    for (int mi = 0; mi < 2; ++mi)
#pragma unroll
        for (int ni = 0; ni < 4; ++ni) {
            qpk[mi][ni][0] = f2b(vacc[mi][ni][0]) | (f2b(vacc[mi][ni][1]) << 16);
            qpk[mi][ni][1] = f2b(vacc[mi][ni][2]) | (f2b(vacc[mi][ni][3]) << 16);
        }

    // prologue staging: tile0 -> x1, tile1 halfA in flight
    convert_half(x1, t, 0, sA);
    issue_half(col, pix0, t, 2, sB);
    convert_half(x1, t, 2, sB);             // one exposed load latency per block
    issue_half(col + (size_t)C * P, pix0, t, 0, sA);   // tile1 half A
    __syncthreads();

    // ---- fused k/v loop; no-max softmax (|s| ~ O(1) by construction); V accumulates
    //      in vacc via scale trick; K-GEMM MI=2. ----
    float lrun[4];
#pragma unroll
    for (int ni = 0; ni < 4; ++ni) lrun[ni] = 0.0f;
    {
        const f32x4 z = {0.0f, 0.0f, 0.0f, 0.0f};
#pragma unroll
        for (int mi = 0; mi < 2; ++mi)
#pragma unroll
            for (int ni = 0; ni < 4; ++ni) vacc[mi][ni] = z;
    }
#pragma unroll 1
    for (int n = 0; n < 4; ++n) {
        unsigned short* const rbuf = (n & 1) ? x0 : x1;   // tile n
        unsigned short* const wbuf = (n & 1) ? x1 : x0;   // tile n+1 lands here
        // K-gemm (MI=2), dot with q immediately
        float s[4];
#pragma unroll
        for (int ni = 0; ni < 4; ++ni) s[ni] = 0.0f;
        {
            f32x4 kacc[2][4];
#pragma unroll
            for (int mi = 0; mi < 2; ++mi) {
                f32x4 bb = *reinterpret_cast<const f32x4*>(bk + row0 + mi * 16 + q * 4);
#pragma unroll
                for (int ni = 0; ni < 4; ++ni) kacc[mi][ni] = bb;
            }
            gemmW<C, XLD, 2, true>(wbf + OFF_WK, rbuf, rb0, a, q, l, kacc);
#pragma unroll
            for (int mi = 0; mi < 2; ++mi)
#pragma unroll
                for (int ni = 0; ni < 4; ++ni) {
                    const unsigned u0 = qpk[mi][ni][0], u1 = qpk[mi][ni][1];
                    float ps = s[ni];
                    ps += b2f(u0 & 0xFFFFu) * kacc[mi][ni][0];
                    ps += b2f(u0 >> 16)     * kacc[mi][ni][1];
                    ps += b2f(u1 & 0xFFFFu) * kacc[mi][ni][2];
                    ps += b2f(u1 >> 16)     * kacc[mi][ni][3];
                    s[ni] = ps;
                }
        }
        // stage: write tile n+1 half A (loads covered by K-gemm), start half B
        if (n < 3) {
            convert_half(wbuf, t, 0, sA);
            issue_half(col + (size_t)(n + 1) * C * P, pix0, t, 2, sB);
        }
        float pp[4];
#pragma unroll
        for (int ni = 0; ni < 4; ++ni) {
            float ps = s[ni];
            ps += __shfl_xor(ps, 16);
            ps += __shfl_xor(ps, 32);
            pp[ni] = __expf(ps * 0.17677669529663687f);  // 1/sqrt(32)
            lrun[ni] += pp[ni];
        }
        // V-GEMM merged into running accumulator: vacc = vacc + pp * (Wv @ x)
#pragma unroll
        for (int ni = 0; ni < 4; ++ni) {
            const float ip = 1.0f / pp[ni];
#pragma unroll
            for (int mi = 0; mi < 2; ++mi) vacc[mi][ni] *= ip;
        }
        gemmW<C, XLD, 2, true>(wbf + OFF_WV, rbuf, rb0, a, q, l, vacc);
#pragma unroll
        for (int ni = 0; ni < 4; ++ni) {
#pragma unroll
            for (int mi = 0; mi < 2; ++mi) vacc[mi][ni] *= pp[ni];
        }
        // stage: write tile n+1 half B (covered by V-gemm), start tile n+2 half A
        if (n < 3) convert_half(wbuf, t, 2, sB);
        if (n < 2) issue_half(col + (size_t)(n + 2) * C * P, pix0, t, 0, sA);
        __syncthreads();
    }
    // normalize; add bv once (sum(attn)=1)
#pragma unroll
    for (int ni = 0; ni < 4; ++ni) {
        float inv = 1.0f / lrun[ni];
#pragma unroll
        for (int mi = 0; mi < 2; ++mi) vacc[mi][ni] *= inv;
    }
#pragma unroll
    for (int mi = 0; mi < 2; ++mi) {
        f32x4 bb = *reinterpret_cast<const f32x4*>(bv + row0 + mi * 16 + q * 4);
#pragma unroll
        for (int ni = 0; ni < 4; ++ni) vacc[mi][ni] += bb;
    }

    // ---- stage attention output into x0 (swizzled), o-GEMM ----
#pragma unroll
    for (int mi = 0; mi < 2; ++mi) {
        const int cb = row0 + mi * 16 + q * 4;
#pragma unroll
        for (int ni = 0; ni < 4; ++ni) {
            const int row = ni * 16 + a;
            const int cs = cb ^ (((2 * ni + (a >> 3)) & 7) << 3);
            unsigned* cell = reinterpret_cast<unsigned*>(x0 + row * XLD + cs);
            cell[0] = f2b(vacc[mi][ni][0]) | (f2b(vacc[mi][ni][1]) << 16);
            cell[1] = f2b(vacc[mi][ni][2]) | (f2b(vacc[mi][ni][3]) << 16);
        }
    }
    __syncthreads();
#pragma unroll
    for (int mi = 0; mi < 2; ++mi) {
        f32x4 bb = *reinterpret_cast<const f32x4*>(bo + row0 + mi * 16 + q * 4);
#pragma unroll
        for (int ni = 0; ni < 4; ++ni) vacc[mi][ni] = bb;
    }
    gemmW<C, XLD, 2, true>(wbf + OFF_WO, x0, rb0, a, q, l, vacc);
#pragma unroll
    for (int mi = 0; mi < 2; ++mi) {
        const int cb = row0 + mi * 16 + q * 4;
#pragma unroll
        for (int ni = 0; ni < 4; ++ni) {
            const int pix = pix0 + ni * 16 + a;
#pragma unroll
            for (int r = 0; r < 4; ++r)
                out[(size_t)(cb + r) * P + pix] = vacc[mi][ni][r];
        }
    }
}

extern "C" void kernel_launch(void* const* d_in, const int* in_sizes, int n_in,
                              void* d_out, int out_size, void* d_ws, size_t ws_size,
                              hipStream_t stream) {
    const float* ego  = (const float*)d_in[0];
    const float* dem  = (const float*)d_in[1];
    const float* col  = (const float*)d_in[2];
    const float* w_d1 = (const float*)d_in[3];
    const float* b_d1 = (const float*)d_in[4];
    const float* w_d2 = (const float*)d_in[5];
    const float* b_d2 = (const float*)d_in[6];
    const float* wq   = (const float*)d_in[7];
    const float* bq   = (const float*)d_in[8];
    const float* wk   = (const float*)d_in[9];
    const float* bk   = (const float*)d_in[10];
    const float* wv   = (const float*)d_in[11];
    const float* bv   = (const float*)d_in[12];
    const float* wo   = (const float*)d_in[13];
    const float* bo   = (const float*)d_in[14];
    const float* pos  = (const float*)d_in[15];
    float* out = (float*)d_out;
    unsigned short* wbf = (unsigned short*)d_ws;

    hipLaunchKernelGGL(cvt_weights, dim3((W_TOTAL + 255) / 256), dim3(256), 0, stream,
                       wq, wk, wv, wo, w_d2, wbf);
    hipLaunchKernelGGL(dca_mfma, dim3(P / BN), dim3(512), 0, stream,
                       ego, dem, col, w_d1, b_d1, b_d2, bq, bk, bv, bo, pos, wbf, out);
}